// Round 1
// baseline (466.437 us; speedup 1.0000x reference)
//
#include <hip/hip_runtime.h>
#include <cmath>

#define FEAT_DIM 1024
#define MM 32
#define KK 256
#define DD 32
#define BB 8192

constexpr float BN_EPS   = 1e-5f;
constexpr float NORM_EPS = 1e-12f;

// ---------- P0: L2-normalize x per (b,m) 32-dim group; zero stats ----------
__global__ void k_norm(const float* __restrict__ x, float* __restrict__ xn,
                       double* __restrict__ stats) {
    if (blockIdx.x == 0 && threadIdx.x < 2 * MM) stats[threadIdx.x] = 0.0;
    int t = blockIdx.x * blockDim.x + threadIdx.x;
    int v = t >> 5;          // (b,m) vector id
    int d = t & 31;
    if (v >= BB * MM) return;
    float val = x[(size_t)v * DD + d];
    float ss = val * val;
    #pragma unroll
    for (int mask = 16; mask >= 1; mask >>= 1) ss += __shfl_xor(ss, mask);
    float n = sqrtf(ss);
    xn[(size_t)v * DD + d] = val / fmaxf(n, NORM_EPS);
}

// ---------- P1: per-m sum/sumsq of sims (einsum pass 1) ----------
template <int BT>
__global__ void k_stats(const float* __restrict__ xn, const float* __restrict__ Ck,
                        double* __restrict__ stats) {
    const int m  = blockIdx.x;
    const int b0 = blockIdx.y * BT;
    const int k  = threadIdx.x;   // 256 threads = 256 codewords

    float c[DD];
    {
        const float4* cp = (const float4*)(Ck + ((size_t)m * KK + k) * DD);
        #pragma unroll
        for (int i = 0; i < 8; ++i) {
            float4 vv = cp[i];
            c[4*i+0]=vv.x; c[4*i+1]=vv.y; c[4*i+2]=vv.z; c[4*i+3]=vv.w;
        }
    }
    float sum = 0.f, sumsq = 0.f;
    for (int bb = 0; bb < BT; ++bb) {
        const float4* xp = (const float4*)(xn + (size_t)(b0+bb) * FEAT_DIM + m * DD);
        float d0=0.f,d1=0.f,d2=0.f,d3=0.f;
        #pragma unroll
        for (int i = 0; i < 8; ++i) {
            float4 xv = xp[i];
            d0 = fmaf(xv.x, c[4*i+0], d0);
            d1 = fmaf(xv.y, c[4*i+1], d1);
            d2 = fmaf(xv.z, c[4*i+2], d2);
            d3 = fmaf(xv.w, c[4*i+3], d3);
        }
        float dot = (d0+d1)+(d2+d3);
        sum += dot;
        sumsq = fmaf(dot, dot, sumsq);
    }
    #pragma unroll
    for (int mask = 32; mask >= 1; mask >>= 1) {
        sum   += __shfl_xor(sum, mask);
        sumsq += __shfl_xor(sumsq, mask);
    }
    __shared__ float ls[4], lq[4];
    const int wid = threadIdx.x >> 6, lane = threadIdx.x & 63;
    if (lane == 0) { ls[wid] = sum; lq[wid] = sumsq; }
    __syncthreads();
    if (threadIdx.x == 0) {
        atomicAdd(&stats[2*m],   (double)((ls[0]+ls[1])+(ls[2]+ls[3])));
        atomicAdd(&stats[2*m+1], (double)((lq[0]+lq[1])+(lq[2]+lq[3])));
    }
}

// ---------- P2: recompute sims, BN-normalize, argmax, softmax, gather ----------
template <int BT>
__global__ void k_main(const float* __restrict__ xn, const float* __restrict__ Ck,
                       const double* __restrict__ stats,
                       float* __restrict__ xhat, float* __restrict__ hard,
                       float* __restrict__ soft) {
    const int m  = blockIdx.x;
    const int b0 = blockIdx.y * BT;
    const int k  = threadIdx.x;
    const int wid = threadIdx.x >> 6, lane = threadIdx.x & 63;

    const double Ninv = 1.0 / ((double)BB * (double)KK);
    const double s  = stats[2*m], q = stats[2*m+1];
    const double mu = s * Ninv;
    const double var = q * Ninv - mu * mu;
    const float mean = (float)mu;
    const float rstd = (float)(1.0 / sqrt(var + (double)BN_EPS));

    float c[DD];
    {
        const float4* cp = (const float4*)(Ck + ((size_t)m * KK + k) * DD);
        #pragma unroll
        for (int i = 0; i < 8; ++i) {
            float4 vv = cp[i];
            c[4*i+0]=vv.x; c[4*i+1]=vv.y; c[4*i+2]=vv.z; c[4*i+3]=vv.w;
        }
    }

    __shared__ float wmaxv[4];
    __shared__ int   wmaxi[4];
    __shared__ float wsum[4];

    for (int bb = 0; bb < BT; ++bb) {
        const int b = b0 + bb;
        const float4* xp = (const float4*)(xn + (size_t)b * FEAT_DIM + m * DD);
        float d0=0.f,d1=0.f,d2=0.f,d3=0.f;
        #pragma unroll
        for (int i = 0; i < 8; ++i) {
            float4 xv = xp[i];
            d0 = fmaf(xv.x, c[4*i+0], d0);
            d1 = fmaf(xv.y, c[4*i+1], d1);
            d2 = fmaf(xv.z, c[4*i+2], d2);
            d3 = fmaf(xv.w, c[4*i+3], d3);
        }
        const float dot = (d0+d1)+(d2+d3);
        const float z = (dot - mean) * rstd;

        // block argmax (first-index tie-break, matching np.argmax)
        float v = z; int idx = k;
        #pragma unroll
        for (int mask = 32; mask >= 1; mask >>= 1) {
            float ov = __shfl_xor(v, mask);
            int   oi = __shfl_xor(idx, mask);
            if (ov > v || (ov == v && oi < idx)) { v = ov; idx = oi; }
        }
        if (lane == 0) { wmaxv[wid] = v; wmaxi[wid] = idx; }
        __syncthreads();
        float bv = wmaxv[0]; int bi = wmaxi[0];
        #pragma unroll
        for (int w = 1; w < 4; ++w) {
            float ov = wmaxv[w]; int oi = wmaxi[w];
            if (ov > bv || (ov == bv && oi < bi)) { bv = ov; bi = oi; }
        }

        const float p = expf(z - bv);
        float ps = p;
        #pragma unroll
        for (int mask = 32; mask >= 1; mask >>= 1) ps += __shfl_xor(ps, mask);
        if (lane == 0) wsum[wid] = ps;
        __syncthreads();
        const float tot = (wsum[0]+wsum[1])+(wsum[2]+wsum[3]);
        const float inv = 1.0f / tot;

        soft[(((size_t)b * MM) + m) * KK + k] = p * inv;
        if (k == 0) hard[(size_t)b * MM + m] = (float)bi;
        if (k < DD) {
            const float cv = Ck[((size_t)m * KK + bi) * DD + k];
            xhat[(size_t)b * FEAT_DIM + m * DD + k] = cv;
        }
        __syncthreads();   // protect wmaxv/wsum for next iteration
    }
}

// ---------- P3: reg_loss[b] = sum_f (xn - xhat)^2 ----------
__global__ void k_reg(const float* __restrict__ xn, const float* __restrict__ xh,
                      float* __restrict__ reg) {
    const int wid = threadIdx.x >> 6, lane = threadIdx.x & 63;
    const int b = blockIdx.x * 4 + wid;
    if (b >= BB) return;
    const float4* a = (const float4*)(xn + (size_t)b * FEAT_DIM);
    const float4* h = (const float4*)(xh + (size_t)b * FEAT_DIM);
    float acc = 0.f;
    #pragma unroll
    for (int i = 0; i < 4; ++i) {
        int j = lane + i * 64;
        float4 av = a[j], hv = h[j];
        float dx = av.x-hv.x, dy = av.y-hv.y, dz = av.z-hv.z, dw = av.w-hv.w;
        acc = fmaf(dx,dx,acc); acc = fmaf(dy,dy,acc);
        acc = fmaf(dz,dz,acc); acc = fmaf(dw,dw,acc);
    }
    #pragma unroll
    for (int mask = 32; mask >= 1; mask >>= 1) acc += __shfl_xor(acc, mask);
    if (lane == 0) reg[b] = acc;
}

extern "C" void kernel_launch(void* const* d_in, const int* in_sizes, int n_in,
                              void* d_out, int out_size, void* d_ws, size_t ws_size,
                              hipStream_t stream) {
    const float* x  = (const float*)d_in[0];
    const float* Ck = (const float*)d_in[1];

    float* out   = (float*)d_out;
    float* xhat  = out;                                   // B*FEAT
    float* hard  = xhat  + (size_t)BB * FEAT_DIM;         // B*M
    float* soft  = hard  + (size_t)BB * MM;               // B*M*K
    float* xnorm = soft  + (size_t)BB * MM * KK;          // B*FEAT
    float* reg   = xnorm + (size_t)BB * FEAT_DIM;         // B

    double* stats = (double*)d_ws;                        // M*2 doubles

    constexpr int BT = 64;
    k_norm<<<(BB * MM * DD) / 256, 256, 0, stream>>>(x, xnorm, stats);
    k_stats<BT><<<dim3(MM, BB / BT), 256, 0, stream>>>(xnorm, Ck, stats);
    k_main<BT><<<dim3(MM, BB / BT), 256, 0, stream>>>(xnorm, Ck, stats, xhat, hard, soft);
    k_reg<<<BB / 4, 256, 0, stream>>>(xnorm, xhat, reg);
}

// Round 2
// 427.864 us; speedup vs baseline: 1.0902x; 1.0902x over previous
//
#include <hip/hip_runtime.h>
#include <cmath>

#define FEAT_DIM 1024
#define MM 32
#define KK 256
#define DD 32
#define BB 8192

constexpr float BN_EPS = 1e-5f;

__device__ __forceinline__ float wave_fsum(float v) {
    #pragma unroll
    for (int s = 32; s >= 1; s >>= 1) v += __shfl_xor(v, s);
    return v;
}
__device__ __forceinline__ float wave_fmax(float v) {
    #pragma unroll
    for (int s = 32; s >= 1; s >>= 1) v = fmaxf(v, __shfl_xor(v, s));
    return v;
}
__device__ __forceinline__ int wave_imin(int v) {
    #pragma unroll
    for (int s = 32; s >= 1; s >>= 1) v = min(v, __shfl_xor(v, s));
    return v;
}

// ---------- P0: L2-normalize x per (b,m); float4 per thread; zero stats ----------
__global__ void k_norm(const float* __restrict__ x, float* __restrict__ xn,
                       double* __restrict__ stats) {
    if (blockIdx.x == 0 && threadIdx.x < 2 * MM) stats[threadIdx.x] = 0.0;
    const int t = blockIdx.x * blockDim.x + threadIdx.x;  // one float4 (8 threads per 32-vec)
    float4 v = ((const float4*)x)[t];
    float ss = v.x*v.x + v.y*v.y + v.z*v.z + v.w*v.w;
    #pragma unroll
    for (int s = 1; s < 8; s <<= 1) ss += __shfl_xor(ss, s);   // 8-lane group reduce
    const float r = 1.0f / fmaxf(sqrtf(ss), 1e-12f);
    float4 o = {v.x*r, v.y*r, v.z*r, v.w*r};
    ((float4*)xn)[t] = o;
}

// ---------- P1a: per-m codebook sums S_m and Gram G_m = C^T C ----------
__global__ void k_gram(const float* __restrict__ Ck, float* __restrict__ G,
                       float* __restrict__ S) {
    __shared__ float CT[DD][KK + 4];   // transposed codebook, 33.3 KB
    const int m = blockIdx.x, part = blockIdx.y;
    const int t = threadIdx.x, wid = t >> 6, lane = t & 63;
    const float4* cp = (const float4*)(Ck + ((size_t)m * KK + t) * DD);
    #pragma unroll
    for (int i = 0; i < 8; ++i) {
        float4 v = cp[i];
        CT[4*i+0][t] = v.x; CT[4*i+1][t] = v.y;
        CT[4*i+2][t] = v.z; CT[4*i+3][t] = v.w;
    }
    __syncthreads();
    #pragma unroll 1
    for (int ei = 0; ei < 32; ++ei) {
        const int e = part * 128 + wid * 32 + ei;
        const int i = e >> 5, j = e & 31;
        float acc = 0.f;
        #pragma unroll
        for (int c4 = 0; c4 < 4; ++c4)
            acc = fmaf(CT[i][lane + 64*c4], CT[j][lane + 64*c4], acc);
        acc = wave_fsum(acc);
        if (lane == 0) G[((size_t)m * DD + i) * DD + j] = acc;
    }
    if (part == 0 && wid == 0) {
        #pragma unroll 1
        for (int d = 0; d < DD; ++d) {
            float a = 0.f;
            #pragma unroll
            for (int c4 = 0; c4 < 4; ++c4) a += CT[d][lane + 64*c4];
            a = wave_fsum(a);
            if (lane == 0) S[m * DD + d] = a;
        }
    }
}

// ---------- P1b: stats via quadratic form: sum = x.S, sumsq = x^T G x ----------
__global__ void k_stats2(const float* __restrict__ xn, const float* __restrict__ G,
                         const float* __restrict__ S, double* __restrict__ stats) {
    const int m = blockIdx.x;
    const int b = blockIdx.y * 256 + threadIdx.x;
    float xv[DD];
    {
        const float4* xp = (const float4*)(xn + (size_t)b * FEAT_DIM + m * DD);
        #pragma unroll
        for (int i = 0; i < 8; ++i) {
            float4 v = xp[i];
            xv[4*i+0]=v.x; xv[4*i+1]=v.y; xv[4*i+2]=v.z; xv[4*i+3]=v.w;
        }
    }
    const float4* Gp = (const float4*)(G + (size_t)m * DD * DD);  // uniform per block
    const float*  Sp = S + m * DD;
    float q = 0.f, s = 0.f;
    #pragma unroll 4
    for (int i = 0; i < DD; ++i) {
        float y = 0.f;
        #pragma unroll
        for (int jv = 0; jv < 8; ++jv) {
            float4 g = Gp[i * 8 + jv];
            y = fmaf(g.x, xv[4*jv+0], y); y = fmaf(g.y, xv[4*jv+1], y);
            y = fmaf(g.z, xv[4*jv+2], y); y = fmaf(g.w, xv[4*jv+3], y);
        }
        q = fmaf(y, xv[i], q);
    }
    #pragma unroll
    for (int i = 0; i < DD; ++i) s = fmaf(Sp[i], xv[i], s);
    q = wave_fsum(q); s = wave_fsum(s);
    __shared__ float lq[4], ls[4];
    const int wid = threadIdx.x >> 6, lane = threadIdx.x & 63;
    if (lane == 0) { lq[wid] = q; ls[wid] = s; }
    __syncthreads();
    if (threadIdx.x == 0) {
        atomicAdd(&stats[2*m],   (double)((ls[0]+ls[1])+(ls[2]+ls[3])));
        atomicAdd(&stats[2*m+1], (double)((lq[0]+lq[1])+(lq[2]+lq[3])));
    }
}

// ---------- P2: wave-per-(b,m): dots, argmax, softmax, gather — no LDS, no barriers ----
template <int BT>
__global__ void k_main(const float* __restrict__ xn, const float* __restrict__ Ck,
                       const double* __restrict__ stats,
                       float* __restrict__ xhat, float* __restrict__ hard,
                       float* __restrict__ soft) {
    const int m = blockIdx.x;
    const int wid = threadIdx.x >> 6, lane = threadIdx.x & 63;

    const double Ninv = 1.0 / ((double)BB * (double)KK);
    const double mu  = stats[2*m] * Ninv;
    const double var = stats[2*m+1] * Ninv - mu * mu;
    const float rstd = (float)(1.0 / sqrt(var + (double)BN_EPS));
    // dot <= 1 (both unit vectors) => uniform softmax stabilizer: p = exp((d-1)*rstd)

    // lane owns codewords k = 4*lane + j, held in registers across the b-loop
    float c[4][DD];
    #pragma unroll
    for (int j = 0; j < 4; ++j) {
        const float4* cp = (const float4*)(Ck + ((size_t)m * KK + 4*lane + j) * DD);
        #pragma unroll
        for (int i = 0; i < 8; ++i) {
            float4 v = cp[i];
            c[j][4*i+0]=v.x; c[j][4*i+1]=v.y; c[j][4*i+2]=v.z; c[j][4*i+3]=v.w;
        }
    }

    const int b_base = blockIdx.y * (4 * BT) + wid;
    #pragma unroll 1
    for (int it = 0; it < BT; ++it) {
        const int b = b_base + 4 * it;
        const int bu = __builtin_amdgcn_readfirstlane(b);   // wave-uniform -> scalar loads
        const float4* xp = (const float4*)(xn + (size_t)bu * FEAT_DIM + m * DD);

        float d0=0.f, d1=0.f, d2=0.f, d3=0.f;
        #pragma unroll
        for (int i = 0; i < 8; ++i) {
            float4 xq = xp[i];
            d0 = fmaf(xq.x, c[0][4*i+0], d0); d0 = fmaf(xq.y, c[0][4*i+1], d0);
            d0 = fmaf(xq.z, c[0][4*i+2], d0); d0 = fmaf(xq.w, c[0][4*i+3], d0);
            d1 = fmaf(xq.x, c[1][4*i+0], d1); d1 = fmaf(xq.y, c[1][4*i+1], d1);
            d1 = fmaf(xq.z, c[1][4*i+2], d1); d1 = fmaf(xq.w, c[1][4*i+3], d1);
            d2 = fmaf(xq.x, c[2][4*i+0], d2); d2 = fmaf(xq.y, c[2][4*i+1], d2);
            d2 = fmaf(xq.z, c[2][4*i+2], d2); d2 = fmaf(xq.w, c[2][4*i+3], d2);
            d3 = fmaf(xq.x, c[3][4*i+0], d3); d3 = fmaf(xq.y, c[3][4*i+1], d3);
            d3 = fmaf(xq.z, c[3][4*i+2], d3); d3 = fmaf(xq.w, c[3][4*i+3], d3);
        }

        // argmax on raw dots (argmax z == argmax d, rstd > 0); first-index tie-break
        const float mx = wave_fmax(fmaxf(fmaxf(d0, d1), fmaxf(d2, d3)));
        int kj = (d0 == mx) ? 4*lane+0 :
                 (d1 == mx) ? 4*lane+1 :
                 (d2 == mx) ? 4*lane+2 :
                 (d3 == mx) ? 4*lane+3 : 0x7fffffff;
        const int bi = wave_imin(kj);

        // softmax with uniform stabilizer (independent of argmax chain)
        const float p0 = __expf((d0 - 1.f) * rstd);
        const float p1 = __expf((d1 - 1.f) * rstd);
        const float p2 = __expf((d2 - 1.f) * rstd);
        const float p3 = __expf((d3 - 1.f) * rstd);
        const float tot = wave_fsum((p0 + p1) + (p2 + p3));
        const float inv = 1.0f / tot;

        float4 o = {p0*inv, p1*inv, p2*inv, p3*inv};
        ((float4*)(soft + ((size_t)b * MM + m) * KK))[lane] = o;
        if (lane == 0) hard[(size_t)b * MM + m] = (float)bi;
        if (lane < 8) {
            float4 cw = ((const float4*)(Ck + ((size_t)m * KK + bi) * DD))[lane];
            ((float4*)(xhat + (size_t)b * FEAT_DIM + m * DD))[lane] = cw;
        }
    }
}

// ---------- P3: reg_loss[b] = sum_f (xn - xhat)^2 ----------
__global__ void k_reg(const float* __restrict__ xn, const float* __restrict__ xh,
                      float* __restrict__ reg) {
    const int wid = threadIdx.x >> 6, lane = threadIdx.x & 63;
    const int b = blockIdx.x * 4 + wid;
    const float4* a = (const float4*)(xn + (size_t)b * FEAT_DIM);
    const float4* h = (const float4*)(xh + (size_t)b * FEAT_DIM);
    float acc = 0.f;
    #pragma unroll
    for (int i = 0; i < 4; ++i) {
        int j = lane + i * 64;
        float4 av = a[j], hv = h[j];
        float dx = av.x-hv.x, dy = av.y-hv.y, dz = av.z-hv.z, dw = av.w-hv.w;
        acc = fmaf(dx,dx,acc); acc = fmaf(dy,dy,acc);
        acc = fmaf(dz,dz,acc); acc = fmaf(dw,dw,acc);
    }
    acc = wave_fsum(acc);
    if (lane == 0) reg[b] = acc;
}

extern "C" void kernel_launch(void* const* d_in, const int* in_sizes, int n_in,
                              void* d_out, int out_size, void* d_ws, size_t ws_size,
                              hipStream_t stream) {
    const float* x  = (const float*)d_in[0];
    const float* Ck = (const float*)d_in[1];

    float* out   = (float*)d_out;
    float* xhat  = out;                                   // B*FEAT
    float* hard  = xhat  + (size_t)BB * FEAT_DIM;         // B*M
    float* soft  = hard  + (size_t)BB * MM;               // B*M*K
    float* xnorm = soft  + (size_t)BB * MM * KK;          // B*FEAT
    float* reg   = xnorm + (size_t)BB * FEAT_DIM;         // B

    double* stats = (double*)d_ws;                        // M*2 doubles
    // G/S scratch lives at the head of `soft` (consumed before k_main rewrites it)
    float* Gbuf = soft;                                   // M*D*D floats
    float* Sbuf = soft + (size_t)MM * DD * DD;            // M*D floats

    k_norm<<<(BB * FEAT_DIM / 4) / 256, 256, 0, stream>>>(x, xnorm, stats);
    k_gram<<<dim3(MM, 8), 256, 0, stream>>>(Ck, Gbuf, Sbuf);
    k_stats2<<<dim3(MM, BB / 256), 256, 0, stream>>>(xnorm, Gbuf, Sbuf, stats);
    constexpr int BT = 16;
    k_main<BT><<<dim3(MM, BB / (4 * BT)), 256, 0, stream>>>(xnorm, Ck, stats, xhat, hard, soft);
    k_reg<<<BB / 4, 256, 0, stream>>>(xnorm, xhat, reg);
}

// Round 4
// 215.036 us; speedup vs baseline: 2.1691x; 1.9897x over previous
//
#include <hip/hip_runtime.h>
#include <cmath>

#define FEAT_DIM 1024
#define MM 32
#define KK 256
#define DD 32
#define BB 8192

constexpr float BN_EPS = 1e-5f;

typedef float f32x4 __attribute__((ext_vector_type(4)));

__device__ __forceinline__ float wave_fsum(float v) {
    #pragma unroll
    for (int s = 32; s >= 1; s >>= 1) v += __shfl_xor(v, s);
    return v;
}
__device__ __forceinline__ float wave_fmax(float v) {
    #pragma unroll
    for (int s = 32; s >= 1; s >>= 1) v = fmaxf(v, __shfl_xor(v, s));
    return v;
}
__device__ __forceinline__ int wave_imin(int v) {
    #pragma unroll
    for (int s = 32; s >= 1; s >>= 1) v = min(v, __shfl_xor(v, s));
    return v;
}

// ---------- P0: L2-normalize x per (b,m); zero stats + reg accumulators ----------
__global__ void k_norm(const float* __restrict__ x, float* __restrict__ xn,
                       double* __restrict__ stats, float* __restrict__ reg) {
    if (blockIdx.x == 0 && threadIdx.x < 2 * MM) stats[threadIdx.x] = 0.0;
    if (blockIdx.x < BB / 256) reg[blockIdx.x * 256 + threadIdx.x] = 0.f;
    const int t = blockIdx.x * blockDim.x + threadIdx.x;  // one float4 (8 threads per 32-vec)
    float4 v = ((const float4*)x)[t];
    float ss = v.x*v.x + v.y*v.y + v.z*v.z + v.w*v.w;
    #pragma unroll
    for (int s = 1; s < 8; s <<= 1) ss += __shfl_xor(ss, s);   // 8-lane group reduce
    const float r = 1.0f / fmaxf(sqrtf(ss), 1e-12f);
    float4 o = {v.x*r, v.y*r, v.z*r, v.w*r};
    ((float4*)xn)[t] = o;
}

// ---------- P1a: per-m codebook sums S_m and Gram G_m = C^T C ----------
__global__ void k_gram(const float* __restrict__ Ck, float* __restrict__ G,
                       float* __restrict__ S) {
    __shared__ float CT[DD][KK + 4];   // transposed codebook, 33.3 KB
    const int m = blockIdx.x, part = blockIdx.y;
    const int t = threadIdx.x, wid = t >> 6, lane = t & 63;
    const float4* cp = (const float4*)(Ck + ((size_t)m * KK + t) * DD);
    #pragma unroll
    for (int i = 0; i < 8; ++i) {
        float4 v = cp[i];
        CT[4*i+0][t] = v.x; CT[4*i+1][t] = v.y;
        CT[4*i+2][t] = v.z; CT[4*i+3][t] = v.w;
    }
    __syncthreads();
    #pragma unroll 1
    for (int ei = 0; ei < 32; ++ei) {
        const int e = part * 128 + wid * 32 + ei;
        const int i = e >> 5, j = e & 31;
        float acc = 0.f;
        #pragma unroll
        for (int c4 = 0; c4 < 4; ++c4)
            acc = fmaf(CT[i][lane + 64*c4], CT[j][lane + 64*c4], acc);
        acc = wave_fsum(acc);
        if (lane == 0) G[((size_t)m * DD + i) * DD + j] = acc;
    }
    if (part == 0 && wid == 0) {
        #pragma unroll 1
        for (int d = 0; d < DD; ++d) {
            float a = 0.f;
            #pragma unroll
            for (int c4 = 0; c4 < 4; ++c4) a += CT[d][lane + 64*c4];
            a = wave_fsum(a);
            if (lane == 0) S[m * DD + d] = a;
        }
    }
}

// ---------- P1b: stats via quadratic form: sum = x.S, sumsq = x^T G x ----------
__global__ void k_stats2(const float* __restrict__ xn, const float* __restrict__ G,
                         const float* __restrict__ S, double* __restrict__ stats) {
    const int m = blockIdx.x;
    const int b = blockIdx.y * 256 + threadIdx.x;
    float xv[DD];
    {
        const float4* xp = (const float4*)(xn + (size_t)b * FEAT_DIM + m * DD);
        #pragma unroll
        for (int i = 0; i < 8; ++i) {
            float4 v = xp[i];
            xv[4*i+0]=v.x; xv[4*i+1]=v.y; xv[4*i+2]=v.z; xv[4*i+3]=v.w;
        }
    }
    const float4* Gp = (const float4*)(G + (size_t)m * DD * DD);  // uniform per block
    const float*  Sp = S + m * DD;
    float q = 0.f, s = 0.f;
    #pragma unroll 4
    for (int i = 0; i < DD; ++i) {
        float y = 0.f;
        #pragma unroll
        for (int jv = 0; jv < 8; ++jv) {
            float4 g = Gp[i * 8 + jv];
            y = fmaf(g.x, xv[4*jv+0], y); y = fmaf(g.y, xv[4*jv+1], y);
            y = fmaf(g.z, xv[4*jv+2], y); y = fmaf(g.w, xv[4*jv+3], y);
        }
        q = fmaf(y, xv[i], q);
    }
    #pragma unroll
    for (int i = 0; i < DD; ++i) s = fmaf(Sp[i], xv[i], s);
    q = wave_fsum(q); s = wave_fsum(s);
    __shared__ float lq[4], ls[4];
    const int wid = threadIdx.x >> 6, lane = threadIdx.x & 63;
    if (lane == 0) { lq[wid] = q; ls[wid] = s; }
    __syncthreads();
    if (threadIdx.x == 0) {
        atomicAdd(&stats[2*m],   (double)((ls[0]+ls[1])+(ls[2]+ls[3])));
        atomicAdd(&stats[2*m+1], (double)((lq[0]+lq[1])+(lq[2]+lq[3])));
    }
}

// ---------- P2: wave-per-(b,m): dots, argmax, softmax, gather, reg — no LDS ----------
template <int BT>
__global__ __launch_bounds__(256, 2)
void k_main(const float* __restrict__ xn, const float* __restrict__ Ck,
            const double* __restrict__ stats,
            float* __restrict__ xhat, float* __restrict__ hard,
            float* __restrict__ soft, float* __restrict__ reg) {
    const int m = blockIdx.x;
    const int wid = threadIdx.x >> 6, lane = threadIdx.x & 63;

    const double Ninv = 1.0 / ((double)BB * (double)KK);
    const double mu  = stats[2*m] * Ninv;
    const double var = stats[2*m+1] * Ninv - mu * mu;
    const float rstd = (float)(1.0 / sqrt(var + (double)BN_EPS));
    // dot <= 1 (both unit vectors) => uniform softmax stabilizer: p = exp((d-1)*rstd)

    // lane owns codewords k = 4*lane + j, held in registers across the b-loop
    float c[4][DD];
    #pragma unroll
    for (int j = 0; j < 4; ++j) {
        const float4* cp = (const float4*)(Ck + ((size_t)m * KK + 4*lane + j) * DD);
        #pragma unroll
        for (int i = 0; i < 8; ++i) {
            float4 v = cp[i];
            c[j][4*i+0]=v.x; c[j][4*i+1]=v.y; c[j][4*i+2]=v.z; c[j][4*i+3]=v.w;
        }
    }

    const int b_base = blockIdx.y * (4 * BT) + wid;

    // software pipeline: prefetch x-slice for the next iteration
    float4 xq[8];
    {
        const int bu = __builtin_amdgcn_readfirstlane(b_base);
        const float4* xp = (const float4*)(xn + (size_t)bu * FEAT_DIM + m * DD);
        #pragma unroll
        for (int i = 0; i < 8; ++i) xq[i] = xp[i];
    }

    #pragma unroll 1
    for (int it = 0; it < BT; ++it) {
        const int b = b_base + 4 * it;

        float4 xnext[8];
        if (it + 1 < BT) {
            const int bu = __builtin_amdgcn_readfirstlane(b + 4);
            const float4* xp = (const float4*)(xn + (size_t)bu * FEAT_DIM + m * DD);
            #pragma unroll
            for (int i = 0; i < 8; ++i) xnext[i] = xp[i];
        }

        float d0=0.f, d1=0.f, d2=0.f, d3=0.f;
        #pragma unroll
        for (int i = 0; i < 8; ++i) {
            const float4 q4 = xq[i];
            d0 = fmaf(q4.x, c[0][4*i+0], d0); d0 = fmaf(q4.y, c[0][4*i+1], d0);
            d0 = fmaf(q4.z, c[0][4*i+2], d0); d0 = fmaf(q4.w, c[0][4*i+3], d0);
            d1 = fmaf(q4.x, c[1][4*i+0], d1); d1 = fmaf(q4.y, c[1][4*i+1], d1);
            d1 = fmaf(q4.z, c[1][4*i+2], d1); d1 = fmaf(q4.w, c[1][4*i+3], d1);
            d2 = fmaf(q4.x, c[2][4*i+0], d2); d2 = fmaf(q4.y, c[2][4*i+1], d2);
            d2 = fmaf(q4.z, c[2][4*i+2], d2); d2 = fmaf(q4.w, c[2][4*i+3], d2);
            d3 = fmaf(q4.x, c[3][4*i+0], d3); d3 = fmaf(q4.y, c[3][4*i+1], d3);
            d3 = fmaf(q4.z, c[3][4*i+2], d3); d3 = fmaf(q4.w, c[3][4*i+3], d3);
        }

        // argmax on raw dots (argmax z == argmax d, rstd > 0); first-index tie-break
        const float mx = wave_fmax(fmaxf(fmaxf(d0, d1), fmaxf(d2, d3)));
        int kj = (d0 == mx) ? 4*lane+0 :
                 (d1 == mx) ? 4*lane+1 :
                 (d2 == mx) ? 4*lane+2 :
                 (d3 == mx) ? 4*lane+3 : 0x7fffffff;
        const int bi = __builtin_amdgcn_readfirstlane(wave_imin(kj));

        // softmax with uniform stabilizer (independent of argmax chain)
        const float p0 = __expf((d0 - 1.f) * rstd);
        const float p1 = __expf((d1 - 1.f) * rstd);
        const float p2 = __expf((d2 - 1.f) * rstd);
        const float p3 = __expf((d3 - 1.f) * rstd);
        const float tot = wave_fsum((p0 + p1) + (p2 + p3));
        const float inv = 1.0f / tot;

        f32x4 o = {p0*inv, p1*inv, p2*inv, p3*inv};
        __builtin_nontemporal_store(o, (f32x4*)(soft + ((size_t)b * MM + m) * KK) + lane);
        if (lane == 0) {
            hard[(size_t)b * MM + m] = (float)bi;
            // reg_loss identity: sum_d (xn - c_bi)^2 = ||xn||^2 + ||c||^2 - 2*dot = 2 - 2*mx
            atomicAdd(&reg[b], 2.f - 2.f * mx);
        }
        if (lane < 8) {
            f32x4 cw = ((const f32x4*)(Ck + ((size_t)m * KK + bi) * DD))[lane];
            __builtin_nontemporal_store(cw, (f32x4*)(xhat + (size_t)b * FEAT_DIM + m * DD) + lane);
        }

        #pragma unroll
        for (int i = 0; i < 8; ++i) xq[i] = xnext[i];
    }
}

extern "C" void kernel_launch(void* const* d_in, const int* in_sizes, int n_in,
                              void* d_out, int out_size, void* d_ws, size_t ws_size,
                              hipStream_t stream) {
    const float* x  = (const float*)d_in[0];
    const float* Ck = (const float*)d_in[1];

    float* out   = (float*)d_out;
    float* xhat  = out;                                   // B*FEAT
    float* hard  = xhat  + (size_t)BB * FEAT_DIM;         // B*M
    float* soft  = hard  + (size_t)BB * MM;               // B*M*K
    float* xnorm = soft  + (size_t)BB * MM * KK;          // B*FEAT
    float* reg   = xnorm + (size_t)BB * FEAT_DIM;         // B

    double* stats = (double*)d_ws;                        // M*2 doubles
    // G/S scratch lives at the head of `soft` (consumed before k_main rewrites it)
    float* Gbuf = soft;                                   // M*D*D floats
    float* Sbuf = soft + (size_t)MM * DD * DD;            // M*D floats

    k_norm<<<(BB * FEAT_DIM / 4) / 256, 256, 0, stream>>>(x, xnorm, stats, reg);
    k_gram<<<dim3(MM, 8), 256, 0, stream>>>(Ck, Gbuf, Sbuf);
    k_stats2<<<dim3(MM, BB / 256), 256, 0, stream>>>(xnorm, Gbuf, Sbuf, stats);
    constexpr int BT = 32;
    k_main<BT><<<dim3(MM, BB / (4 * BT)), 256, 0, stream>>>(xnorm, Ck, stats, xhat, hard, soft, reg);
}

// Round 5
// 210.456 us; speedup vs baseline: 2.2163x; 1.0218x over previous
//
#include <hip/hip_runtime.h>
#include <cmath>

#define FEAT_DIM 1024
#define MM 32
#define KK 256
#define DD 32
#define BB 8192

constexpr float BN_EPS = 1e-5f;

typedef float f32x4 __attribute__((ext_vector_type(4)));

__device__ __forceinline__ float wave_fsum(float v) {
    #pragma unroll
    for (int s = 32; s >= 1; s >>= 1) v += __shfl_xor(v, s);
    return v;
}
__device__ __forceinline__ float wave_fmax(float v) {
    #pragma unroll
    for (int s = 32; s >= 1; s >>= 1) v = fmaxf(v, __shfl_xor(v, s));
    return v;
}

// ---------- P0: L2-normalize x per (b,m); zero stats + reg accumulators ----------
__global__ void k_norm(const float* __restrict__ x, float* __restrict__ xn,
                       double* __restrict__ stats, float* __restrict__ reg) {
    if (blockIdx.x == 0 && threadIdx.x < 2 * MM) stats[threadIdx.x] = 0.0;
    if (blockIdx.x < BB / 256) reg[blockIdx.x * 256 + threadIdx.x] = 0.f;
    const int t = blockIdx.x * blockDim.x + threadIdx.x;  // one float4 (8 threads per 32-vec)
    float4 v = ((const float4*)x)[t];
    float ss = v.x*v.x + v.y*v.y + v.z*v.z + v.w*v.w;
    #pragma unroll
    for (int s = 1; s < 8; s <<= 1) ss += __shfl_xor(ss, s);   // 8-lane group reduce
    const float r = 1.0f / fmaxf(sqrtf(ss), 1e-12f);
    float4 o = {v.x*r, v.y*r, v.z*r, v.w*r};
    ((float4*)xn)[t] = o;
}

// ---------- P1a: per-m codebook sums S_m and Gram G_m = C^T C ----------
__global__ void k_gram(const float* __restrict__ Ck, float* __restrict__ G,
                       float* __restrict__ S) {
    __shared__ float CT[DD][KK + 4];   // transposed codebook, 33.3 KB
    const int m = blockIdx.x, part = blockIdx.y;
    const int t = threadIdx.x, wid = t >> 6, lane = t & 63;
    const float4* cp = (const float4*)(Ck + ((size_t)m * KK + t) * DD);
    #pragma unroll
    for (int i = 0; i < 8; ++i) {
        float4 v = cp[i];
        CT[4*i+0][t] = v.x; CT[4*i+1][t] = v.y;
        CT[4*i+2][t] = v.z; CT[4*i+3][t] = v.w;
    }
    __syncthreads();
    #pragma unroll 1
    for (int ei = 0; ei < 32; ++ei) {
        const int e = part * 128 + wid * 32 + ei;
        const int i = e >> 5, j = e & 31;
        float acc = 0.f;
        #pragma unroll
        for (int c4 = 0; c4 < 4; ++c4)
            acc = fmaf(CT[i][lane + 64*c4], CT[j][lane + 64*c4], acc);
        acc = wave_fsum(acc);
        if (lane == 0) G[((size_t)m * DD + i) * DD + j] = acc;
    }
    if (part == 0 && wid == 0) {
        #pragma unroll 1
        for (int d = 0; d < DD; ++d) {
            float a = 0.f;
            #pragma unroll
            for (int c4 = 0; c4 < 4; ++c4) a += CT[d][lane + 64*c4];
            a = wave_fsum(a);
            if (lane == 0) S[m * DD + d] = a;
        }
    }
}

// ---------- P1b: stats via quadratic form: sum = x.S, sumsq = x^T G x ----------
__global__ void k_stats2(const float* __restrict__ xn, const float* __restrict__ G,
                         const float* __restrict__ S, double* __restrict__ stats) {
    const int m = blockIdx.x;
    const int b = blockIdx.y * 256 + threadIdx.x;
    float xv[DD];
    {
        const float4* xp = (const float4*)(xn + (size_t)b * FEAT_DIM + m * DD);
        #pragma unroll
        for (int i = 0; i < 8; ++i) {
            float4 v = xp[i];
            xv[4*i+0]=v.x; xv[4*i+1]=v.y; xv[4*i+2]=v.z; xv[4*i+3]=v.w;
        }
    }
    const float4* Gp = (const float4*)(G + (size_t)m * DD * DD);  // uniform per block
    const float*  Sp = S + m * DD;
    float q = 0.f, s = 0.f;
    #pragma unroll 4
    for (int i = 0; i < DD; ++i) {
        float y = 0.f;
        #pragma unroll
        for (int jv = 0; jv < 8; ++jv) {
            float4 g = Gp[i * 8 + jv];
            y = fmaf(g.x, xv[4*jv+0], y); y = fmaf(g.y, xv[4*jv+1], y);
            y = fmaf(g.z, xv[4*jv+2], y); y = fmaf(g.w, xv[4*jv+3], y);
        }
        q = fmaf(y, xv[i], q);
    }
    #pragma unroll
    for (int i = 0; i < DD; ++i) s = fmaf(Sp[i], xv[i], s);
    q = wave_fsum(q); s = wave_fsum(s);
    __shared__ float lq[4], ls[4];
    const int wid = threadIdx.x >> 6, lane = threadIdx.x & 63;
    if (lane == 0) { lq[wid] = q; ls[wid] = s; }
    __syncthreads();
    if (threadIdx.x == 0) {
        atomicAdd(&stats[2*m],   (double)((ls[0]+ls[1])+(ls[2]+ls[3])));
        atomicAdd(&stats[2*m+1], (double)((lq[0]+lq[1])+(lq[2]+lq[3])));
    }
}

// ---------- P2: wave-per-(b,m): dots, ballot-argmax, softmax, gather, reg ----------
template <int BT>
__global__ __launch_bounds__(256, 2)
void k_main(const float* __restrict__ xn, const float* __restrict__ Ck,
            const double* __restrict__ stats,
            float* __restrict__ xhat, float* __restrict__ hard,
            float* __restrict__ soft, float* __restrict__ reg) {
    const int m = blockIdx.x;
    const int wid = threadIdx.x >> 6, lane = threadIdx.x & 63;

    const double Ninv = 1.0 / ((double)BB * (double)KK);
    const double mu  = stats[2*m] * Ninv;
    const double var = stats[2*m+1] * Ninv - mu * mu;
    const float rstd = (float)(1.0 / sqrt(var + (double)BN_EPS));
    // dot <= 1 (both unit vectors) => uniform softmax stabilizer: p = exp((d-1)*rstd)

    // lane owns codewords k = 4*lane + j, register-resident across the b-loop
    float c[4][DD];
    #pragma unroll
    for (int j = 0; j < 4; ++j) {
        const float4* cp = (const float4*)(Ck + ((size_t)m * KK + 4*lane + j) * DD);
        #pragma unroll
        for (int i = 0; i < 8; ++i) {
            float4 v = cp[i];
            c[j][4*i+0]=v.x; c[j][4*i+1]=v.y; c[j][4*i+2]=v.z; c[j][4*i+3]=v.w;
        }
    }

    const int b_base = blockIdx.y * (4 * BT) + wid;

    auto loadslice = [&](float4 (&q)[8], int b) {
        const int bu = __builtin_amdgcn_readfirstlane(b);
        const float4* xp = (const float4*)(xn + (size_t)bu * FEAT_DIM + m * DD);
        #pragma unroll
        for (int i = 0; i < 8; ++i) q[i] = xp[i];
    };

    auto process = [&](const float4 (&q)[8], int b) {
        float d0=0.f, d1=0.f, d2=0.f, d3=0.f;
        #pragma unroll
        for (int i = 0; i < 8; ++i) {
            const float4 q4 = q[i];
            d0 = fmaf(q4.x, c[0][4*i+0], d0); d0 = fmaf(q4.y, c[0][4*i+1], d0);
            d0 = fmaf(q4.z, c[0][4*i+2], d0); d0 = fmaf(q4.w, c[0][4*i+3], d0);
            d1 = fmaf(q4.x, c[1][4*i+0], d1); d1 = fmaf(q4.y, c[1][4*i+1], d1);
            d1 = fmaf(q4.z, c[1][4*i+2], d1); d1 = fmaf(q4.w, c[1][4*i+3], d1);
            d2 = fmaf(q4.x, c[2][4*i+0], d2); d2 = fmaf(q4.y, c[2][4*i+1], d2);
            d2 = fmaf(q4.z, c[2][4*i+2], d2); d2 = fmaf(q4.w, c[2][4*i+3], d2);
            d3 = fmaf(q4.x, c[3][4*i+0], d3); d3 = fmaf(q4.y, c[3][4*i+1], d3);
            d3 = fmaf(q4.z, c[3][4*i+2], d3); d3 = fmaf(q4.w, c[3][4*i+3], d3);
        }

        // softmax with uniform stabilizer — chain independent of argmax chain
        const float p0 = __expf((d0 - 1.f) * rstd);
        const float p1 = __expf((d1 - 1.f) * rstd);
        const float p2 = __expf((d2 - 1.f) * rstd);
        const float p3 = __expf((d3 - 1.f) * rstd);

        // argmax: wave-max, then ballot + scalar ffs (no second shuffle chain)
        const float mx = wave_fmax(fmaxf(fmaxf(d0, d1), fmaxf(d2, d3)));
        const unsigned long long m0 = __ballot(d0 == mx);
        const unsigned long long m1 = __ballot(d1 == mx);
        const unsigned long long m2 = __ballot(d2 == mx);
        const unsigned long long m3 = __ballot(d3 == mx);
        const int k0 = m0 ? 4*__builtin_ctzll(m0)+0 : 0x7fffffff;
        const int k1 = m1 ? 4*__builtin_ctzll(m1)+1 : 0x7fffffff;
        const int k2 = m2 ? 4*__builtin_ctzll(m2)+2 : 0x7fffffff;
        const int k3 = m3 ? 4*__builtin_ctzll(m3)+3 : 0x7fffffff;
        const int bi = min(min(k0, k1), min(k2, k3));   // scalar, first-index tie-break

        const float tot = wave_fsum((p0 + p1) + (p2 + p3));
        const float inv = 1.0f / tot;

        f32x4 o = {p0*inv, p1*inv, p2*inv, p3*inv};
        __builtin_nontemporal_store(o, (f32x4*)(soft + ((size_t)b * MM + m) * KK) + lane);
        if (lane == 0) {
            hard[(size_t)b * MM + m] = (float)bi;
            // reg identity: sum_d (xn - c_bi)^2 = ||xn||^2 + ||c||^2 - 2*dot = 2 - 2*mx
            atomicAdd(&reg[b], 2.f - 2.f * mx);
        }
        if (lane < 8) {
            f32x4 cw = ((const f32x4*)(Ck + ((size_t)m * KK + bi) * DD))[lane];
            __builtin_nontemporal_store(cw, (f32x4*)(xhat + (size_t)b * FEAT_DIM + m * DD) + lane);
        }
    };

    // ping-pong double-buffer, no register copies
    float4 A[8], Bv[8];
    loadslice(A, b_base);
    #pragma unroll 1
    for (int it = 0; it < BT; it += 2) {
        loadslice(Bv, b_base + 4 * (it + 1));           // BT even: it+1 < BT always
        process(A, b_base + 4 * it);
        if (it + 2 < BT) loadslice(A, b_base + 4 * (it + 2));
        process(Bv, b_base + 4 * (it + 1));
    }
}

extern "C" void kernel_launch(void* const* d_in, const int* in_sizes, int n_in,
                              void* d_out, int out_size, void* d_ws, size_t ws_size,
                              hipStream_t stream) {
    const float* x  = (const float*)d_in[0];
    const float* Ck = (const float*)d_in[1];

    float* out   = (float*)d_out;
    float* xhat  = out;                                   // B*FEAT
    float* hard  = xhat  + (size_t)BB * FEAT_DIM;         // B*M
    float* soft  = hard  + (size_t)BB * MM;               // B*M*K
    float* xnorm = soft  + (size_t)BB * MM * KK;          // B*FEAT
    float* reg   = xnorm + (size_t)BB * FEAT_DIM;         // B

    double* stats = (double*)d_ws;                        // M*2 doubles
    // G/S scratch lives at the head of `soft` (consumed before k_main rewrites it)
    float* Gbuf = soft;                                   // M*D*D floats
    float* Sbuf = soft + (size_t)MM * DD * DD;            // M*D floats

    k_norm<<<(BB * FEAT_DIM / 4) / 256, 256, 0, stream>>>(x, xnorm, stats, reg);
    k_gram<<<dim3(MM, 8), 256, 0, stream>>>(Ck, Gbuf, Sbuf);
    k_stats2<<<dim3(MM, BB / 256), 256, 0, stream>>>(xnorm, Gbuf, Sbuf, stats);
    constexpr int BT = 32;
    k_main<BT><<<dim3(MM, BB / (4 * BT)), 256, 0, stream>>>(xnorm, Ck, stats, xhat, hard, soft, reg);
}

// Round 6
// 168.000 us; speedup vs baseline: 2.7764x; 1.2527x over previous
//
#include <hip/hip_runtime.h>
#include <cmath>

#define FEAT_DIM 1024
#define MM 32
#define KK 256
#define DD 32
#define BB 8192

constexpr float BN_EPS = 1e-5f;

typedef float f32x4 __attribute__((ext_vector_type(4)));

__device__ __forceinline__ float wave_fsum(float v) {
    #pragma unroll
    for (int s = 32; s >= 1; s >>= 1) v += __shfl_xor(v, s);
    return v;
}

// ---- DPP-based full-wave reductions: VALU-rate, result broadcast via SGPR ----
template <int CTRL, int RM = 0xf>
__device__ __forceinline__ float dppf(float v) {
    int r = __builtin_amdgcn_update_dpp(__builtin_bit_cast(int, v),
                                        __builtin_bit_cast(int, v),
                                        CTRL, RM, 0xf, false);
    return __builtin_bit_cast(float, r);
}
// 0xB1 quad_perm(1,0,3,2)=xor1; 0x4E quad_perm(2,3,0,1)=xor2; 0x141 row_half_mirror;
// 0x140 row_mirror; 0x142 row_bcast15 (rows 1,3); 0x143 row_bcast31 (rows 2,3)
__device__ __forceinline__ float wave_dpp_max(float v) {
    v = fmaxf(v, dppf<0xB1>(v));
    v = fmaxf(v, dppf<0x4E>(v));
    v = fmaxf(v, dppf<0x141>(v));
    v = fmaxf(v, dppf<0x140>(v));
    v = fmaxf(v, dppf<0x142, 0xa>(v));
    v = fmaxf(v, dppf<0x143, 0xc>(v));
    return __builtin_bit_cast(float, __builtin_amdgcn_readlane(__builtin_bit_cast(int, v), 63));
}
__device__ __forceinline__ float wave_dpp_sum(float v) {
    v += dppf<0xB1>(v);
    v += dppf<0x4E>(v);
    v += dppf<0x141>(v);
    v += dppf<0x140>(v);
    v += dppf<0x142, 0xa>(v);   // masked rows hold stale values; lane63 path is exact
    v += dppf<0x143, 0xc>(v);
    return __builtin_bit_cast(float, __builtin_amdgcn_readlane(__builtin_bit_cast(int, v), 63));
}

// ---------- P0: L2-normalize x per (b,m); zero stats ----------
__global__ void k_norm(const float* __restrict__ x, float* __restrict__ xn,
                       double* __restrict__ stats) {
    if (blockIdx.x == 0 && threadIdx.x < 2 * MM) stats[threadIdx.x] = 0.0;
    const int t = blockIdx.x * blockDim.x + threadIdx.x;  // one float4 (8 threads per 32-vec)
    float4 v = ((const float4*)x)[t];
    float ss = v.x*v.x + v.y*v.y + v.z*v.z + v.w*v.w;
    #pragma unroll
    for (int s = 1; s < 8; s <<= 1) ss += __shfl_xor(ss, s);   // 8-lane group reduce
    const float r = 1.0f / fmaxf(sqrtf(ss), 1e-12f);
    float4 o = {v.x*r, v.y*r, v.z*r, v.w*r};
    ((float4*)xn)[t] = o;
}

// ---------- P1a: per-m codebook sums S_m and Gram G_m = C^T C ----------
__global__ void k_gram(const float* __restrict__ Ck, float* __restrict__ G,
                       float* __restrict__ S) {
    __shared__ float CT[DD][KK + 4];   // transposed codebook, 33.3 KB
    const int m = blockIdx.x, part = blockIdx.y;
    const int t = threadIdx.x, wid = t >> 6, lane = t & 63;
    const float4* cp = (const float4*)(Ck + ((size_t)m * KK + t) * DD);
    #pragma unroll
    for (int i = 0; i < 8; ++i) {
        float4 v = cp[i];
        CT[4*i+0][t] = v.x; CT[4*i+1][t] = v.y;
        CT[4*i+2][t] = v.z; CT[4*i+3][t] = v.w;
    }
    __syncthreads();
    #pragma unroll 1
    for (int ei = 0; ei < 32; ++ei) {
        const int e = part * 128 + wid * 32 + ei;
        const int i = e >> 5, j = e & 31;
        float acc = 0.f;
        #pragma unroll
        for (int c4 = 0; c4 < 4; ++c4)
            acc = fmaf(CT[i][lane + 64*c4], CT[j][lane + 64*c4], acc);
        acc = wave_fsum(acc);
        if (lane == 0) G[((size_t)m * DD + i) * DD + j] = acc;
    }
    if (part == 0 && wid == 0) {
        #pragma unroll 1
        for (int d = 0; d < DD; ++d) {
            float a = 0.f;
            #pragma unroll
            for (int c4 = 0; c4 < 4; ++c4) a += CT[d][lane + 64*c4];
            a = wave_fsum(a);
            if (lane == 0) S[m * DD + d] = a;
        }
    }
}

// ---------- P1b: stats via quadratic form: sum = x.S, sumsq = x^T G x ----------
__global__ void k_stats2(const float* __restrict__ xn, const float* __restrict__ G,
                         const float* __restrict__ S, double* __restrict__ stats) {
    const int m = blockIdx.x;
    const int b = blockIdx.y * 256 + threadIdx.x;
    float xv[DD];
    {
        const float4* xp = (const float4*)(xn + (size_t)b * FEAT_DIM + m * DD);
        #pragma unroll
        for (int i = 0; i < 8; ++i) {
            float4 v = xp[i];
            xv[4*i+0]=v.x; xv[4*i+1]=v.y; xv[4*i+2]=v.z; xv[4*i+3]=v.w;
        }
    }
    const float4* Gp = (const float4*)(G + (size_t)m * DD * DD);  // uniform per block
    const float*  Sp = S + m * DD;
    float q = 0.f, s = 0.f;
    #pragma unroll 4
    for (int i = 0; i < DD; ++i) {
        float y = 0.f;
        #pragma unroll
        for (int jv = 0; jv < 8; ++jv) {
            float4 g = Gp[i * 8 + jv];
            y = fmaf(g.x, xv[4*jv+0], y); y = fmaf(g.y, xv[4*jv+1], y);
            y = fmaf(g.z, xv[4*jv+2], y); y = fmaf(g.w, xv[4*jv+3], y);
        }
        q = fmaf(y, xv[i], q);
    }
    #pragma unroll
    for (int i = 0; i < DD; ++i) s = fmaf(Sp[i], xv[i], s);
    q = wave_fsum(q); s = wave_fsum(s);
    __shared__ float lq[4], ls[4];
    const int wid = threadIdx.x >> 6, lane = threadIdx.x & 63;
    if (lane == 0) { lq[wid] = q; ls[wid] = s; }
    __syncthreads();
    if (threadIdx.x == 0) {
        atomicAdd(&stats[2*m],   (double)((ls[0]+ls[1])+(ls[2]+ls[3])));
        atomicAdd(&stats[2*m+1], (double)((lq[0]+lq[1])+(lq[2]+lq[3])));
    }
}

// ---------- P2: wave-per-(b,m): dots, DPP reductions, ballot-argmax ----------
template <int BT>
__global__ __launch_bounds__(256, 2)
void k_main(const float* __restrict__ xn, const float* __restrict__ Ck,
            const double* __restrict__ stats,
            float* __restrict__ xhat, float* __restrict__ hard,
            float* __restrict__ soft, float* __restrict__ part) {
    const int m = blockIdx.x;
    const int wid = threadIdx.x >> 6, lane = threadIdx.x & 63;

    const double Ninv = 1.0 / ((double)BB * (double)KK);
    const double mu  = stats[2*m] * Ninv;
    const double var = stats[2*m+1] * Ninv - mu * mu;
    const float rstd = (float)(1.0 / sqrt(var + (double)BN_EPS));
    // dot <= 1 (both unit vectors) => uniform softmax stabilizer: p = exp((d-1)*rstd)

    // lane owns codewords k = 4*lane + j, register-resident across the b-loop
    float c[4][DD];
    #pragma unroll
    for (int j = 0; j < 4; ++j) {
        const float4* cp = (const float4*)(Ck + ((size_t)m * KK + 4*lane + j) * DD);
        #pragma unroll
        for (int i = 0; i < 8; ++i) {
            float4 v = cp[i];
            c[j][4*i+0]=v.x; c[j][4*i+1]=v.y; c[j][4*i+2]=v.z; c[j][4*i+3]=v.w;
        }
    }

    const int b_base = blockIdx.y * (4 * BT) + wid;

    auto loadslice = [&](float4 (&q)[8], int b) {
        const int bu = __builtin_amdgcn_readfirstlane(b);
        const float4* xp = (const float4*)(xn + (size_t)bu * FEAT_DIM + m * DD);
        #pragma unroll
        for (int i = 0; i < 8; ++i) q[i] = xp[i];
    };

    auto process = [&](const float4 (&q)[8], int b) {
        float d0=0.f, d1=0.f, d2=0.f, d3=0.f;
        #pragma unroll
        for (int i = 0; i < 8; ++i) {
            const float4 q4 = q[i];
            d0 = fmaf(q4.x, c[0][4*i+0], d0); d0 = fmaf(q4.y, c[0][4*i+1], d0);
            d0 = fmaf(q4.z, c[0][4*i+2], d0); d0 = fmaf(q4.w, c[0][4*i+3], d0);
            d1 = fmaf(q4.x, c[1][4*i+0], d1); d1 = fmaf(q4.y, c[1][4*i+1], d1);
            d1 = fmaf(q4.z, c[1][4*i+2], d1); d1 = fmaf(q4.w, c[1][4*i+3], d1);
            d2 = fmaf(q4.x, c[2][4*i+0], d2); d2 = fmaf(q4.y, c[2][4*i+1], d2);
            d2 = fmaf(q4.z, c[2][4*i+2], d2); d2 = fmaf(q4.w, c[2][4*i+3], d2);
            d3 = fmaf(q4.x, c[3][4*i+0], d3); d3 = fmaf(q4.y, c[3][4*i+1], d3);
            d3 = fmaf(q4.z, c[3][4*i+2], d3); d3 = fmaf(q4.w, c[3][4*i+3], d3);
        }

        // softmax with uniform stabilizer — VALU chain, independent of argmax chain
        const float p0 = __expf((d0 - 1.f) * rstd);
        const float p1 = __expf((d1 - 1.f) * rstd);
        const float p2 = __expf((d2 - 1.f) * rstd);
        const float p3 = __expf((d3 - 1.f) * rstd);

        // argmax: DPP wave-max (SGPR broadcast), then ballot + scalar ffs
        const float mx = wave_dpp_max(fmaxf(fmaxf(d0, d1), fmaxf(d2, d3)));
        const unsigned long long m0 = __ballot(d0 == mx);
        const unsigned long long m1 = __ballot(d1 == mx);
        const unsigned long long m2 = __ballot(d2 == mx);
        const unsigned long long m3 = __ballot(d3 == mx);
        const int k0 = m0 ? 4*__builtin_ctzll(m0)+0 : 0x7fffffff;
        const int k1 = m1 ? 4*__builtin_ctzll(m1)+1 : 0x7fffffff;
        const int k2 = m2 ? 4*__builtin_ctzll(m2)+2 : 0x7fffffff;
        const int k3 = m3 ? 4*__builtin_ctzll(m3)+3 : 0x7fffffff;
        const int bi = min(min(k0, k1), min(k2, k3));   // first-index tie-break

        const float tot = wave_dpp_sum((p0 + p1) + (p2 + p3));
        const float inv = 1.0f / tot;

        f32x4 o = {p0*inv, p1*inv, p2*inv, p3*inv};
        __builtin_nontemporal_store(o, (f32x4*)(soft + ((size_t)b * MM + m) * KK) + lane);
        if (lane == 0) {
            hard[(size_t)b * MM + m] = (float)bi;
            // reg identity: sum_d (xn - c_bi)^2 = ||xn||^2 + ||c||^2 - 2*dot = 2 - 2*mx
            part[(size_t)m * BB + b] = 2.f - 2.f * mx;   // plain store, no atomics
        }
        if (lane < 8) {
            f32x4 cw = ((const f32x4*)(Ck + ((size_t)m * KK + bi) * DD))[lane];
            __builtin_nontemporal_store(cw, (f32x4*)(xhat + (size_t)b * FEAT_DIM + m * DD) + lane);
        }
    };

    // ping-pong double-buffer, no register copies
    float4 A[8], Bv[8];
    loadslice(A, b_base);
    #pragma unroll 1
    for (int it = 0; it < BT; it += 2) {
        loadslice(Bv, b_base + 4 * (it + 1));           // BT even: it+1 < BT always
        process(A, b_base + 4 * it);
        if (it + 2 < BT) loadslice(A, b_base + 4 * (it + 2));
        process(Bv, b_base + 4 * (it + 1));
    }
}

// ---------- P3: reg[b] = sum_m part[m][b] ----------
__global__ void k_regsum(const float* __restrict__ part, float* __restrict__ reg) {
    const int b = blockIdx.x * 256 + threadIdx.x;
    float a = 0.f;
    #pragma unroll
    for (int mm = 0; mm < MM; ++mm) a += part[(size_t)mm * BB + b];
    reg[b] = a;
}

extern "C" void kernel_launch(void* const* d_in, const int* in_sizes, int n_in,
                              void* d_out, int out_size, void* d_ws, size_t ws_size,
                              hipStream_t stream) {
    const float* x  = (const float*)d_in[0];
    const float* Ck = (const float*)d_in[1];

    float* out   = (float*)d_out;
    float* xhat  = out;                                   // B*FEAT
    float* hard  = xhat  + (size_t)BB * FEAT_DIM;         // B*M
    float* soft  = hard  + (size_t)BB * MM;               // B*M*K
    float* xnorm = soft  + (size_t)BB * MM * KK;          // B*FEAT
    float* reg   = xnorm + (size_t)BB * FEAT_DIM;         // B

    double* stats = (double*)d_ws;                        // M*2 doubles
    float* partb  = (float*)d_ws + 256;                   // M*B floats (1 MB) scratch
    // G/S scratch lives at the head of `soft` (consumed before k_main rewrites it)
    float* Gbuf = soft;                                   // M*D*D floats
    float* Sbuf = soft + (size_t)MM * DD * DD;            // M*D floats

    k_norm<<<(BB * FEAT_DIM / 4) / 256, 256, 0, stream>>>(x, xnorm, stats);
    k_gram<<<dim3(MM, 8), 256, 0, stream>>>(Ck, Gbuf, Sbuf);
    k_stats2<<<dim3(MM, BB / 256), 256, 0, stream>>>(xnorm, Gbuf, Sbuf, stats);
    constexpr int BT = 32;
    k_main<BT><<<dim3(MM, BB / (4 * BT)), 256, 0, stream>>>(xnorm, Ck, stats, xhat, hard, soft, partb);
    k_regsum<<<BB / 256, 256, 0, stream>>>(partb, reg);
}